// Round 9
// baseline (392.618 us; speedup 1.0000x reference)
//
#include <hip/hip_runtime.h>

typedef unsigned int uint;
typedef unsigned short ushort;
typedef __attribute__((ext_vector_type(8))) short bf16x8;
typedef __attribute__((ext_vector_type(4))) float f32x4;

// ---------- bf16 helpers (RNE) ----------
__device__ __forceinline__ ushort f2b(float f) {
  uint u = __float_as_uint(f);
  return (ushort)((u + 0x7fffu + ((u >> 16) & 1u)) >> 16);
}
__device__ __forceinline__ uint pk2(float lo, float hi) {
  return (uint)f2b(lo) | ((uint)f2b(hi) << 16);
}
__device__ __forceinline__ void ub2(uint u, float& lo, float& hi) {
  lo = __uint_as_float(u << 16);
  hi = __uint_as_float(u & 0xffff0000u);
}

// ================= bucketed CSR build (no global atomics) =================
__global__ __launch_bounds__(256) void k_bcount(const int* __restrict__ col,
                                                int* __restrict__ G, int E, int C) {
  __shared__ int cnt[256];
  cnt[threadIdx.x] = 0;
  __syncthreads();
  int e0 = blockIdx.x * C, e1 = min(E, e0 + C);
  for (int e = e0 + threadIdx.x; e < e1; e += 256)
    atomicAdd(&cnt[__builtin_nontemporal_load(col + e) >> 9], 1);
  __syncthreads();
  G[blockIdx.x * 256 + threadIdx.x] = cnt[threadIdx.x];
}

__global__ __launch_bounds__(256) void k_bscan(const int* __restrict__ G,
                                               int* __restrict__ OFF,
                                               int* __restrict__ bstart, int E) {
  const int b = threadIdx.x;
  int tot = 0;
  for (int blk = 0; blk < 256; ++blk) tot += G[blk * 256 + b];
  __shared__ int s[256];
  s[b] = tot;
  __syncthreads();
  for (int off = 1; off < 256; off <<= 1) {
    int v = s[b];
    int a = (b >= off) ? s[b - off] : 0;
    __syncthreads();
    s[b] = v + a;
    __syncthreads();
  }
  int start = (b > 0) ? s[b - 1] : 0;
  bstart[b] = start;
  if (b == 255) bstart[256] = s[255];
  int run = start;
  for (int blk = 0; blk < 256; ++blk) {
    OFF[blk * 256 + b] = run;
    run += G[blk * 256 + b];
  }
}

__global__ __launch_bounds__(256) void k_bstage(const int* __restrict__ row,
                                                const int* __restrict__ col,
                                                const int* __restrict__ OFF,
                                                int* __restrict__ stag, int E, int C) {
  __shared__ int cur[256];
  cur[threadIdx.x] = OFF[blockIdx.x * 256 + threadIdx.x];
  __syncthreads();
  int e0 = blockIdx.x * C, e1 = min(E, e0 + C);
  for (int e = e0 + threadIdx.x; e < e1; e += 256) {
    int r = __builtin_nontemporal_load(row + e);
    int c = __builtin_nontemporal_load(col + e);
    int pos = atomicAdd(&cur[c >> 9], 1);
    stag[pos] = (r << 9) | (c & 511);
  }
}

__global__ __launch_bounds__(256) void k_bcsr(const int* __restrict__ stag,
                                              const int* __restrict__ bstart,
                                              int* __restrict__ colptr,
                                              int* __restrict__ csr, int N, int E) {
  __shared__ int ldeg[512];
  __shared__ int sd[256];
  const int t = threadIdx.x;
  const int b = blockIdx.x;
  const int c0 = b << 9;
  const int nn = min(512, N - c0);
  const int estart = bstart[b], eend = bstart[b + 1];
  ldeg[t] = 0;
  ldeg[t + 256] = 0;
  __syncthreads();
  for (int i = estart + t; i < eend; i += 256)
    atomicAdd(&ldeg[stag[i] & 511], 1);
  __syncthreads();
  int v0 = ldeg[2 * t], v1 = ldeg[2 * t + 1];
  sd[t] = v0 + v1;
  __syncthreads();
  for (int off = 1; off < 256; off <<= 1) {
    int v = sd[t];
    int a = (t >= off) ? sd[t - off] : 0;
    __syncthreads();
    sd[t] = v + a;
    __syncthreads();
  }
  int a0 = estart + ((t > 0) ? sd[t - 1] : 0);
  int a1 = a0 + v0;
  __syncthreads();
  ldeg[2 * t] = a0;
  ldeg[2 * t + 1] = a1;
  if (2 * t < nn) colptr[c0 + 2 * t] = a0;
  if (2 * t + 1 < nn) colptr[c0 + 2 * t + 1] = a1;
  if (t == 0 && c0 + nn == N) colptr[N] = E;
  __syncthreads();
  for (int i = estart + t; i < eend; i += 256) {
    int pk = stag[i];
    int pos = atomicAdd(&ldeg[pk & 511], 1);
    csr[pos] = pk >> 9;
  }
}

__global__ void k_dinv_cp(const int* __restrict__ colptr, float* __restrict__ dinv,
                          float* __restrict__ sdeg, int N) {
  int i = blockIdx.x * blockDim.x + threadIdx.x;
  if (i < N) {
    float d = (float)(colptr[i + 1] - colptr[i] + 1);
    dinv[i] = rsqrtf(d);
    sdeg[i] = sqrtf(d);
  }
}

// ---------------- W -> bf16 ----------------
__global__ void k_f2b(const float* __restrict__ in, ushort* __restrict__ o, int n8) {
  int i = blockIdx.x * blockDim.x + threadIdx.x;
  if (i >= n8) return;
  const float4* p = (const float4*)(in + (size_t)i * 8);
  float4 A = p[0], B = p[1];
  uint4 u;
  u.x = pk2(A.x, A.y);
  u.y = pk2(A.z, A.w);
  u.z = pk2(B.x, B.y);
  u.w = pk2(B.z, B.w);
  ((uint4*)o)[i] = u;
}

// ---------------- fused projection tail: one 16-row tile ----------------
__device__ __forceinline__ void proj_tail(
    const ushort* ylds, float* ssl, float* otile,
    const ushort* __restrict__ wk, const float* __restrict__ biask,
    const float* __restrict__ sdeg, int donorm, float* __restrict__ out,
    int nbase, int koff, int N, int ost, int tid) {
  const int wave = tid >> 6;
  const int lane = tid & 63;
  const int l15 = lane & 15, lhi = lane >> 4;
  f32x4 acc0 = (f32x4)0.f, acc1 = (f32x4)0.f;
  const ushort* ap = ylds + l15 * 136 + lhi * 8;
  const ushort* b0p = wk + ((wave * 32 + l15) << 7) + lhi * 8;
  const ushort* b1p = b0p + (16 << 7);
#pragma unroll
  for (int kk = 0; kk < 4; ++kk) {
    bf16x8 a = *(const bf16x8*)(ap + kk * 32);
    bf16x8 b0 = *(const bf16x8*)(b0p + kk * 32);
    bf16x8 b1 = *(const bf16x8*)(b1p + kk * 32);
    acc0 = __builtin_amdgcn_mfma_f32_16x16x32_bf16(a, b0, acc0, 0, 0, 0);
    acc1 = __builtin_amdgcn_mfma_f32_16x16x32_bf16(a, b1, acc1, 0, 0, 0);
  }
  float s[4];
#pragma unroll
  for (int r = 0; r < 4; ++r) {
    int rg = nbase + lhi * 4 + r;
    s[r] = sdeg[rg < N ? rg : N - 1];
  }
  float bv0 = biask[wave * 32 + l15];
  float bv1 = biask[wave * 32 + 16 + l15];
  float ps[4];
#pragma unroll
  for (int r = 0; r < 4; ++r) {
    acc0[r] = acc0[r] * s[r] + bv0;
    acc1[r] = acc1[r] * s[r] + bv1;
    ps[r] = acc0[r] * acc0[r] + acc1[r] * acc1[r];
  }
#pragma unroll
  for (int m = 1; m < 16; m <<= 1) {
#pragma unroll
    for (int r = 0; r < 4; ++r) ps[r] += __shfl_xor(ps[r], m, 64);
  }
  if (l15 == 0) {
#pragma unroll
    for (int r = 0; r < 4; ++r) ssl[wave * 16 + lhi * 4 + r] = ps[r];
  }
  __syncthreads();
  float sc[4];
#pragma unroll
  for (int r = 0; r < 4; ++r) {
    int rl = lhi * 4 + r;
    float tot = ssl[rl] + ssl[16 + rl] + ssl[32 + rl] + ssl[48 + rl];
    sc[r] = (donorm == 1) ? 1.0f / fmaxf(sqrtf(tot), 1e-12f) : 1.0f;
  }
#pragma unroll
  for (int r = 0; r < 4; ++r) {
    int rl = lhi * 4 + r;
    otile[rl * 132 + wave * 32 + l15] = acc0[r] * sc[r];
    otile[rl * 132 + wave * 32 + 16 + l15] = acc1[r] * sc[r];
  }
  __syncthreads();
  {
    int rr = tid >> 5, q = tid & 31;
    if (rr < 16 && nbase + rr < N) {  // 256 threads cover 8 rows/pass
      f32x4 vv = *(const f32x4*)&otile[rr * 132 + q * 4];
      __builtin_nontemporal_store(
          vv, (f32x4*)(out + (size_t)(nbase + rr) * ost + koff + q * 4));
    }
    int idx = tid + 256;
    rr = idx >> 5;
    q = idx & 31;
    if (rr < 16 && nbase + rr < N) {
      f32x4 vv = *(const f32x4*)&otile[rr * 132 + q * 4];
      __builtin_nontemporal_store(
          vv, (f32x4*)(out + (size_t)(nbase + rr) * ost + koff + q * 4));
    }
  }
}

// ---------------- weightless bf16 hop (8-lane groups, 32 nodes/block) ----------------
__device__ __forceinline__ void add8(uint4 v, float* a) {
  float t0, t1;
  ub2(v.x, t0, t1); a[0] += t0; a[1] += t1;
  ub2(v.y, t0, t1); a[2] += t0; a[3] += t1;
  ub2(v.z, t0, t1); a[4] += t0; a[5] += t1;
  ub2(v.w, t0, t1); a[6] += t0; a[7] += t1;
}

__global__ __launch_bounds__(256) void k_hopproj(
    const ushort* __restrict__ xin, ushort* __restrict__ yout,
    const ushort* __restrict__ wk, const float* __restrict__ biask,
    const float* __restrict__ sdeg, const float* __restrict__ dinv,
    const int* __restrict__ colptr, const int* __restrict__ csr,
    const int* __restrict__ normp, float* __restrict__ out,
    int koff, int N, int ost, int writeY) {
  __shared__ ushort ylds[32 * 136];
  __shared__ float ssl[64];
  __shared__ float otile[16 * 132];
  const int tid = threadIdx.x;
  const int grp = tid >> 3;      // 32 node groups
  const int l = tid & 7;         // 8 lanes per node
  const int nbase = blockIdx.x * 32;
  const int node = nbase + grp;
  const int nc = node < N ? node : N - 1;

  float di = dinv[nc];
  float w2 = di * di;
  // self term: lane owns dims [l*8, l*8+8) and [64+l*8, 64+l*8+8)
  const ushort* xrow = xin + (size_t)nc * 128;
  uint4 vA = *(const uint4*)(xrow + l * 8);
  uint4 vB = *(const uint4*)(xrow + 64 + l * 8);
  float aA[8], aB[8];
  {
    float t0, t1;
    ub2(vA.x, t0, t1); aA[0] = t0; aA[1] = t1;
    ub2(vA.y, t0, t1); aA[2] = t0; aA[3] = t1;
    ub2(vA.z, t0, t1); aA[4] = t0; aA[5] = t1;
    ub2(vA.w, t0, t1); aA[6] = t0; aA[7] = t1;
    ub2(vB.x, t0, t1); aB[0] = t0; aB[1] = t1;
    ub2(vB.y, t0, t1); aB[2] = t0; aB[3] = t1;
    ub2(vB.z, t0, t1); aB[4] = t0; aB[5] = t1;
    ub2(vB.w, t0, t1); aB[6] = t0; aB[7] = t1;
  }

  int p = colptr[nc], p1 = colptr[nc + 1];
  for (; p + 4 <= p1; p += 4) {
    int s0 = __builtin_nontemporal_load(csr + p);
    int s1 = __builtin_nontemporal_load(csr + p + 1);
    int s2 = __builtin_nontemporal_load(csr + p + 2);
    int s3 = __builtin_nontemporal_load(csr + p + 3);
    const ushort* r0 = xin + (size_t)s0 * 128;
    const ushort* r1 = xin + (size_t)s1 * 128;
    const ushort* r2 = xin + (size_t)s2 * 128;
    const ushort* r3 = xin + (size_t)s3 * 128;
    uint4 xA0 = *(const uint4*)(r0 + l * 8);
    uint4 xB0 = *(const uint4*)(r0 + 64 + l * 8);
    uint4 xA1 = *(const uint4*)(r1 + l * 8);
    uint4 xB1 = *(const uint4*)(r1 + 64 + l * 8);
    uint4 xA2 = *(const uint4*)(r2 + l * 8);
    uint4 xB2 = *(const uint4*)(r2 + 64 + l * 8);
    uint4 xA3 = *(const uint4*)(r3 + l * 8);
    uint4 xB3 = *(const uint4*)(r3 + 64 + l * 8);
    add8(xA0, aA); add8(xB0, aB);
    add8(xA1, aA); add8(xB1, aB);
    add8(xA2, aA); add8(xB2, aB);
    add8(xA3, aA); add8(xB3, aB);
  }
  for (; p < p1; ++p) {
    int s0 = __builtin_nontemporal_load(csr + p);
    const ushort* r0 = xin + (size_t)s0 * 128;
    uint4 xA0 = *(const uint4*)(r0 + l * 8);
    uint4 xB0 = *(const uint4*)(r0 + 64 + l * 8);
    add8(xA0, aA); add8(xB0, aB);
  }
  uint4 oA, oB;
  oA.x = pk2(w2 * aA[0], w2 * aA[1]);
  oA.y = pk2(w2 * aA[2], w2 * aA[3]);
  oA.z = pk2(w2 * aA[4], w2 * aA[5]);
  oA.w = pk2(w2 * aA[6], w2 * aA[7]);
  oB.x = pk2(w2 * aB[0], w2 * aB[1]);
  oB.y = pk2(w2 * aB[2], w2 * aB[3]);
  oB.z = pk2(w2 * aB[4], w2 * aB[5]);
  oB.w = pk2(w2 * aB[6], w2 * aB[7]);
  if (writeY && node < N) {
    ushort* yrow = yout + (size_t)node * 128;
    *(uint4*)(yrow + l * 8) = oA;
    *(uint4*)(yrow + 64 + l * 8) = oB;
  }
  *(uint4*)(ylds + grp * 136 + l * 8) = oA;
  *(uint4*)(ylds + grp * 136 + 64 + l * 8) = oB;
  __syncthreads();

  const int donorm = normp[0];
  proj_tail(ylds, ssl, otile, wk, biask, sdeg, donorm, out, nbase, koff, N,
            ost, tid);
  __syncthreads();
  proj_tail(ylds + 16 * 136, ssl, otile, wk, biask, sdeg, donorm, out,
            nbase + 16, koff, N, ost, tid);
}

// ---------------- y0 = dinv*h (bf16) + fused projection of hop 0 ----------------
__global__ __launch_bounds__(256) void k_y0proj(
    const float* __restrict__ h, ushort* __restrict__ yout,
    const ushort* __restrict__ wk, const float* __restrict__ biask,
    const float* __restrict__ sdeg, const float* __restrict__ dinv,
    const int* __restrict__ normp, float* __restrict__ out, int N, int ost) {
  __shared__ ushort ylds[32 * 136];
  __shared__ float ssl[64];
  __shared__ float otile[16 * 132];
  const int tid = threadIdx.x;
  const int grp = tid >> 3;
  const int l = tid & 7;
  const int nbase = blockIdx.x * 32;
  const int node = nbase + grp;
  const int nc = node < N ? node : N - 1;

  float d = dinv[nc];
  const float* hrow = h + (size_t)nc * 128;
  // lane owns dims {l*4..+3, 32+l*4.., 64+l*4.., 96+l*4..}
#pragma unroll
  for (int chunk = 0; chunk < 4; ++chunk) {
    int d0 = chunk * 32 + l * 4;
    float4 f = *(const float4*)(hrow + d0);
    uint2 u;
    u.x = pk2(f.x * d, f.y * d);
    u.y = pk2(f.z * d, f.w * d);
    *(uint2*)(ylds + grp * 136 + d0) = u;
    ushort* yrow = yout + (size_t)nc * 128;
    *(uint2*)(yrow + d0) = u;
  }
  __syncthreads();

  const int donorm = normp[0];
  proj_tail(ylds, ssl, otile, wk, biask, sdeg, donorm, out, nbase, 0, N, ost,
            tid);
  __syncthreads();
  proj_tail(ylds + 16 * 136, ssl, otile, wk, biask, sdeg, donorm, out,
            nbase + 16, 0, N, ost, tid);
}

// =================== fp32 fallback path (kept intact) ===================
__global__ void k_zero(uint4* __restrict__ p, int n4) {
  int stride = gridDim.x * blockDim.x;
  for (int i = blockIdx.x * blockDim.x + threadIdx.x; i < n4; i += stride)
    p[i] = make_uint4(0, 0, 0, 0);
}

__global__ void k_deg(const int* __restrict__ col, int* __restrict__ deg, int E) {
  int i = blockIdx.x * blockDim.x + threadIdx.x;
  if (i < E) atomicAdd(&deg[col[i]], 1);
}

__global__ void k_dinv_deg(const int* __restrict__ deg, float* __restrict__ dinv,
                           float* __restrict__ sdeg, int N) {
  int i = blockIdx.x * blockDim.x + threadIdx.x;
  if (i < N) {
    float d = (float)(deg[i] + 1);
    dinv[i] = rsqrtf(d);
    sdeg[i] = sqrtf(d);
  }
}

__global__ void k_scan1(const int* __restrict__ deg, int* __restrict__ colptr,
                        int* __restrict__ part, int N) {
  __shared__ int sd[256];
  int t = threadIdx.x;
  int base = blockIdx.x * 1024 + t * 4;
  int v0 = base + 0 < N ? deg[base + 0] : 0;
  int v1 = base + 1 < N ? deg[base + 1] : 0;
  int v2 = base + 2 < N ? deg[base + 2] : 0;
  int v3 = base + 3 < N ? deg[base + 3] : 0;
  sd[t] = v0 + v1 + v2 + v3;
  __syncthreads();
  for (int off = 1; off < 256; off <<= 1) {
    int val = sd[t];
    int add = (t >= off) ? sd[t - off] : 0;
    __syncthreads();
    sd[t] = val + add;
    __syncthreads();
  }
  int excl = (t > 0) ? sd[t - 1] : 0;
  if (t == 255) part[blockIdx.x] = sd[255];
  if (base + 0 < N) colptr[base + 0] = excl;
  if (base + 1 < N) colptr[base + 1] = excl + v0;
  if (base + 2 < N) colptr[base + 2] = excl + v0 + v1;
  if (base + 3 < N) colptr[base + 3] = excl + v0 + v1 + v2;
}

__global__ void k_scan2(int* __restrict__ part, int nb) {
  __shared__ int sd[1024];
  int t = threadIdx.x;
  sd[t] = (t < nb) ? part[t] : 0;
  __syncthreads();
  for (int off = 1; off < 1024; off <<= 1) {
    int val = sd[t];
    int add = (t >= off) ? sd[t - off] : 0;
    __syncthreads();
    sd[t] = val + add;
    __syncthreads();
  }
  if (t < nb) part[t] = (t > 0) ? sd[t - 1] : 0;
}

__global__ void k_scan3(int* __restrict__ colptr, const int* __restrict__ part, int N, int E) {
  int i = blockIdx.x * blockDim.x + threadIdx.x;
  if (i < N) colptr[i] += part[i >> 10];
  if (i == 0) colptr[N] = E;
}

__global__ void k_fill(const int* __restrict__ row, const int* __restrict__ col,
                       const int* __restrict__ colptr, int* __restrict__ cursor,
                       const float* __restrict__ dinv, int2* __restrict__ csr, int E) {
  int stride = gridDim.x * blockDim.x;
  for (int i = blockIdx.x * blockDim.x + threadIdx.x; i < E; i += stride) {
    int r = row[i], c = col[i];
    int pos = colptr[c] + atomicAdd(&cursor[c], 1);
    int2 v;
    v.x = r;
    v.y = __float_as_int(dinv[r] * dinv[c]);
    csr[pos] = v;
  }
}

__global__ void k_wt(const float* __restrict__ W, float* __restrict__ Wt, int total) {
  int i = blockIdx.x * blockDim.x + threadIdx.x;
  if (i < total) {
    int k = i >> 14, rem = i & 16383, h = rem >> 7, f = rem & 127;
    Wt[(k << 14) + f * 128 + h] = W[i];
  }
}

__global__ __launch_bounds__(256) void k_hop(
    const float* __restrict__ xsrc, int xstride,
    float* __restrict__ out, int dst_off, int ost,
    const int* __restrict__ colptr, const int2* __restrict__ csr,
    const float* __restrict__ dinv, int N) {
  int gid = blockIdx.x * blockDim.x + threadIdx.x;
  int node = gid >> 5, lane = gid & 31;
  if (node >= N) return;
  float di = dinv[node];
  float4 acc = *(const float4*)(xsrc + (size_t)node * xstride + lane * 4);
  float w = di * di;
  acc.x *= w; acc.y *= w; acc.z *= w; acc.w *= w;
  int p1 = colptr[node + 1];
  for (int p = colptr[node]; p < p1; ++p) {
    int2 ev = csr[p];
    float v = __int_as_float(ev.y);
    float4 x = *(const float4*)(xsrc + (size_t)ev.x * xstride + lane * 4);
    acc.x += v * x.x; acc.y += v * x.y; acc.z += v * x.z; acc.w += v * x.w;
  }
  *(float4*)(out + (size_t)node * ost + dst_off + lane * 4) = acc;
}

__global__ __launch_bounds__(256) void k_gemm(
    const float* __restrict__ h, const float* __restrict__ Wt_g,
    const float* __restrict__ bias, const int* __restrict__ normp,
    float* __restrict__ out, int N, int ost) {
  __shared__ float Wt[128 * 128];
  __shared__ float xl[32 * 128];
  const int k = blockIdx.y;
  const int row0 = blockIdx.x * 32;
  const int tid = threadIdx.x;
  const float4* Wg4 = (const float4*)(Wt_g + ((size_t)k << 14));
  float4* Wt4 = (float4*)Wt;
#pragma unroll
  for (int i = 0; i < 16; ++i) Wt4[tid + 256 * i] = Wg4[tid + 256 * i];
  const float* xs = (k == 0) ? h : (out + k * 128);
  const int xst = (k == 0) ? 128 : ost;
  float4* xl4 = (float4*)xl;
#pragma unroll
  for (int i = 0; i < 4; ++i) {
    int idx = tid + 256 * i;
    int r = idx >> 5, fq = idx & 31;
    int rg = row0 + r;
    if (rg >= N) rg = N - 1;
    xl4[idx] = *((const float4*)(xs + (size_t)rg * xst) + fq);
  }
  __syncthreads();
  const int hq = tid & 31;
  const int rq = tid >> 5;
  float acc[4][4] = {{0.f}};
  const float* xb = xl + rq * 4 * 128;
#pragma unroll 4
  for (int f = 0; f < 128; ++f) {
    float4 wv = *(const float4*)(Wt + f * 128 + hq * 4);
    float x0 = xb[f];
    float x1 = xb[128 + f];
    float x2 = xb[256 + f];
    float x3 = xb[384 + f];
    acc[0][0] += x0 * wv.x; acc[0][1] += x0 * wv.y; acc[0][2] += x0 * wv.z; acc[0][3] += x0 * wv.w;
    acc[1][0] += x1 * wv.x; acc[1][1] += x1 * wv.y; acc[1][2] += x1 * wv.z; acc[1][3] += x1 * wv.w;
    acc[2][0] += x2 * wv.x; acc[2][1] += x2 * wv.y; acc[2][2] += x2 * wv.z; acc[2][3] += x2 * wv.w;
    acc[3][0] += x3 * wv.x; acc[3][1] += x3 * wv.y; acc[3][2] += x3 * wv.z; acc[3][3] += x3 * wv.w;
  }
  float4 bv = *((const float4*)(bias + (size_t)k * 128) + hq);
#pragma unroll
  for (int rl = 0; rl < 4; ++rl) {
    acc[rl][0] += bv.x; acc[rl][1] += bv.y; acc[rl][2] += bv.z; acc[rl][3] += bv.w;
  }
  float ss[4];
#pragma unroll
  for (int rl = 0; rl < 4; ++rl)
    ss[rl] = acc[rl][0] * acc[rl][0] + acc[rl][1] * acc[rl][1] +
             acc[rl][2] * acc[rl][2] + acc[rl][3] * acc[rl][3];
#pragma unroll
  for (int m = 1; m < 32; m <<= 1) {
#pragma unroll
    for (int rl = 0; rl < 4; ++rl) ss[rl] += __shfl_xor(ss[rl], m, 64);
  }
  const int donorm = normp[0];
#pragma unroll
  for (int rl = 0; rl < 4; ++rl) {
    float sc = 1.0f;
    if (donorm == 1) sc = 1.0f / fmaxf(sqrtf(ss[rl]), 1e-12f);
    int rg = row0 + rq * 4 + rl;
    if (rg < N) {
      float4 oo;
      oo.x = acc[rl][0] * sc; oo.y = acc[rl][1] * sc;
      oo.z = acc[rl][2] * sc; oo.w = acc[rl][3] * sc;
      *((float4*)(out + (size_t)rg * ost + k * 128) + hq) = oo;
    }
  }
}

extern "C" void kernel_launch(void* const* d_in, const int* in_sizes, int n_in,
                              void* d_out, int out_size, void* d_ws, size_t ws_size,
                              hipStream_t stream) {
  const float* h = (const float*)d_in[0];
  const int* ei = (const int*)d_in[1];
  const int* normp = (const int*)d_in[2];
  const float* W = (const float*)d_in[3];
  const float* bias = (const float*)d_in[4];
  float* out = (float*)d_out;

  const int N = in_sizes[0] / 128;
  const int E = in_sizes[1] / 2;
  const int KP1 = in_sizes[3] / (128 * 128);
  const int OST = KP1 * 128;
  const int* row = ei;
  const int* col = ei + E;

  char* ws = (char*)d_ws;
  size_t used = 0;
  auto carve = [&](size_t bytes) {
    char* p = ws + used;
    used += (bytes + 255) & ~(size_t)255;
    return p;
  };
  int* colptr = (int*)carve((size_t)(N + 1) * 4);
  float* dinv = (float*)carve((size_t)N * 4);
  float* sdeg = (float*)carve((size_t)N * 4);

  const size_t al = 255;
  const size_t bucketable = (size_t)N <= 131072 ? 1 : 0;
  const size_t gB = 256 * 256 * 4;
  const size_t needBf = used + 2 * ((gB + al) & ~al) + 4096 +
                        2 * (((size_t)E * 4 + al) & ~al) +
                        (((size_t)KP1 * 128 * 128 * 2 + al) & ~al) +
                        2 * (((size_t)N * 128 * 2 + al) & ~al);

  if (bucketable && ws_size >= needBf) {
    // ---------------- bf16 fused path, bucketed CSR ----------------
    int* G = (int*)carve(gB);
    int* OFF = (int*)carve(gB);
    int* bstart = (int*)carve(4096);
    int* stag = (int*)carve((size_t)E * 4);
    int* csr = (int*)carve((size_t)E * 4);
    ushort* Wb = (ushort*)carve((size_t)KP1 * 128 * 128 * 2);
    ushort* bufA = (ushort*)carve((size_t)N * 128 * 2);
    ushort* bufB = (ushort*)carve((size_t)N * 128 * 2);

    const int C = (E + 255) / 256;
    const int NBUK = (N + 511) >> 9;
    const int nblk = (N + 255) / 256;

    k_bcount<<<256, 256, 0, stream>>>(col, G, E, C);
    k_bscan<<<1, 256, 0, stream>>>(G, OFF, bstart, E);
    k_bstage<<<256, 256, 0, stream>>>(row, col, OFF, stag, E, C);
    k_bcsr<<<NBUK, 256, 0, stream>>>(stag, bstart, colptr, csr, N, E);
    k_dinv_cp<<<nblk, 256, 0, stream>>>(colptr, dinv, sdeg, N);
    k_f2b<<<(KP1 * 2048 + 255) / 256, 256, 0, stream>>>(W, Wb, KP1 * 2048);

    int gb = (N + 31) / 32;
    k_y0proj<<<gb, 256, 0, stream>>>(h, bufA, Wb, bias, sdeg, dinv, normp, out,
                                     N, OST);
    ushort* cur = bufA;
    ushort* nxt = bufB;
    for (int kk = 1; kk < KP1; ++kk) {
      k_hopproj<<<gb, 256, 0, stream>>>(
          cur, nxt, Wb + (kk << 14), bias + kk * 128, sdeg, dinv, colptr, csr,
          normp, out, kk * 128, N, OST, (kk < KP1 - 1) ? 1 : 0);
      ushort* t = cur; cur = nxt; nxt = t;
    }
  } else {
    // ---------------- fp32 fallback (old preprocessing) ----------------
    int* deg = (int*)carve((size_t)N * 4);
    int* part = (int*)carve(4096);
    int* cursor = (int*)carve((size_t)N * 4);
    int2* csr2 = (int2*)carve((size_t)E * 8);
    float* Wt_g = (float*)carve((size_t)KP1 * 128 * 128 * 4);
    const int eb = (E + 255) / 256;
    const int nblk = (N + 255) / 256;
    k_zero<<<32, 256, 0, stream>>>((uint4*)deg, (N + 3) / 4);
    k_zero<<<32, 256, 0, stream>>>((uint4*)cursor, (N + 3) / 4);
    k_deg<<<eb, 256, 0, stream>>>(col, deg, E);
    k_dinv_deg<<<nblk, 256, 0, stream>>>(deg, dinv, sdeg, N);
    int nb = (N + 1023) / 1024;
    k_scan1<<<nb, 256, 0, stream>>>(deg, colptr, part, N);
    k_scan2<<<1, 1024, 0, stream>>>(part, nb);
    k_scan3<<<nblk, 256, 0, stream>>>(colptr, part, N, E);
    k_fill<<<1024, 256, 0, stream>>>(row, col, colptr, cursor, dinv, csr2, E);
    k_wt<<<(KP1 * 16384 + 255) / 256, 256, 0, stream>>>(W, Wt_g, KP1 * 16384);
    int hopBlocks = (N * 32 + 255) / 256;
    for (int kk = 1; kk < KP1; ++kk) {
      const float* src = (kk == 1) ? h : (out + (kk - 1) * 128);
      int st = (kk == 1) ? 128 : OST;
      k_hop<<<hopBlocks, 256, 0, stream>>>(src, st, out, kk * 128, OST,
                                           colptr, csr2, dinv, N);
    }
    k_gemm<<<dim3((N + 31) / 32, KP1), 256, 0, stream>>>(h, Wt_g, bias, normp,
                                                         out, N, OST);
  }
}

// Round 10
// 367.298 us; speedup vs baseline: 1.0689x; 1.0689x over previous
//
#include <hip/hip_runtime.h>

typedef unsigned int uint;
typedef unsigned short ushort;
typedef __attribute__((ext_vector_type(8))) short bf16x8;
typedef __attribute__((ext_vector_type(4))) float f32x4;

// ---------- bf16 helpers (RNE) ----------
__device__ __forceinline__ ushort f2b(float f) {
  uint u = __float_as_uint(f);
  return (ushort)((u + 0x7fffu + ((u >> 16) & 1u)) >> 16);
}
__device__ __forceinline__ uint pk2(float lo, float hi) {
  return (uint)f2b(lo) | ((uint)f2b(hi) << 16);
}
__device__ __forceinline__ void ub2(uint u, float& lo, float& hi) {
  lo = __uint_as_float(u << 16);
  hi = __uint_as_float(u & 0xffff0000u);
}

// ================= bucketed CSR build (no global atomics) =================
// bucket(c) = c >> 9  (512 nodes per bucket; requires N <= 131072)

// also converts W -> bf16 in its first 32 blocks (fused f2b)
__global__ __launch_bounds__(256) void k_bcount(const int* __restrict__ col,
                                                int* __restrict__ G, int E, int C,
                                                const float* __restrict__ W,
                                                ushort* __restrict__ Wb, int wn8) {
  __shared__ int cnt[256];
  cnt[threadIdx.x] = 0;
  __syncthreads();
  int e0 = blockIdx.x * C, e1 = min(E, e0 + C);
  for (int e = e0 + threadIdx.x; e < e1; e += 256)
    atomicAdd(&cnt[__builtin_nontemporal_load(col + e) >> 9], 1);
  __syncthreads();
  G[blockIdx.x * 256 + threadIdx.x] = cnt[threadIdx.x];

  // fused W -> bf16 (wn8 = KP1*2048 float8-groups)
  int i = blockIdx.x * 256 + threadIdx.x;
  if (i < wn8) {
    const float4* p = (const float4*)(W + (size_t)i * 8);
    float4 A = p[0], B = p[1];
    uint4 u;
    u.x = pk2(A.x, A.y);
    u.y = pk2(A.z, A.w);
    u.z = pk2(B.x, B.y);
    u.w = pk2(B.z, B.w);
    ((uint4*)Wb)[i] = u;
  }
}

__global__ __launch_bounds__(256) void k_bscan(const int* __restrict__ G,
                                               int* __restrict__ OFF,
                                               int* __restrict__ bstart, int E) {
  const int b = threadIdx.x;
  int tot = 0;
  for (int blk = 0; blk < 256; ++blk) tot += G[blk * 256 + b];
  __shared__ int s[256];
  s[b] = tot;
  __syncthreads();
  for (int off = 1; off < 256; off <<= 1) {
    int v = s[b];
    int a = (b >= off) ? s[b - off] : 0;
    __syncthreads();
    s[b] = v + a;
    __syncthreads();
  }
  int start = (b > 0) ? s[b - 1] : 0;
  bstart[b] = start;
  if (b == 255) bstart[256] = s[255];
  int run = start;
  for (int blk = 0; blk < 256; ++blk) {
    OFF[blk * 256 + b] = run;
    run += G[blk * 256 + b];
  }
}

__global__ __launch_bounds__(256) void k_bstage(const int* __restrict__ row,
                                                const int* __restrict__ col,
                                                const int* __restrict__ OFF,
                                                int* __restrict__ stag, int E, int C) {
  __shared__ int cur[256];
  cur[threadIdx.x] = OFF[blockIdx.x * 256 + threadIdx.x];
  __syncthreads();
  int e0 = blockIdx.x * C, e1 = min(E, e0 + C);
  for (int e = e0 + threadIdx.x; e < e1; e += 256) {
    int r = __builtin_nontemporal_load(row + e);
    int c = __builtin_nontemporal_load(col + e);
    int pos = atomicAdd(&cur[c >> 9], 1);
    stag[pos] = (r << 9) | (c & 511);
  }
}

// one block per bucket: degree hist -> scan -> colptr slice + dinv/sdeg + csr scatter
__global__ __launch_bounds__(256) void k_bcsr(const int* __restrict__ stag,
                                              const int* __restrict__ bstart,
                                              int* __restrict__ colptr,
                                              int* __restrict__ csr,
                                              float* __restrict__ dinv,
                                              float* __restrict__ sdeg,
                                              int N, int E) {
  __shared__ int ldeg[512];
  __shared__ int sd[256];
  const int t = threadIdx.x;
  const int b = blockIdx.x;
  const int c0 = b << 9;
  const int nn = min(512, N - c0);
  const int estart = bstart[b], eend = bstart[b + 1];
  ldeg[t] = 0;
  ldeg[t + 256] = 0;
  __syncthreads();
  for (int i = estart + t; i < eend; i += 256)
    atomicAdd(&ldeg[stag[i] & 511], 1);
  __syncthreads();
  int v0 = ldeg[2 * t], v1 = ldeg[2 * t + 1];
  sd[t] = v0 + v1;
  __syncthreads();
  for (int off = 1; off < 256; off <<= 1) {
    int v = sd[t];
    int a = (t >= off) ? sd[t - off] : 0;
    __syncthreads();
    sd[t] = v + a;
    __syncthreads();
  }
  int a0 = estart + ((t > 0) ? sd[t - 1] : 0);
  int a1 = a0 + v0;
  __syncthreads();
  ldeg[2 * t] = a0;
  ldeg[2 * t + 1] = a1;
  if (2 * t < nn) {
    colptr[c0 + 2 * t] = a0;
    float d = (float)(v0 + 1);
    dinv[c0 + 2 * t] = rsqrtf(d);
    sdeg[c0 + 2 * t] = sqrtf(d);
  }
  if (2 * t + 1 < nn) {
    colptr[c0 + 2 * t + 1] = a1;
    float d = (float)(v1 + 1);
    dinv[c0 + 2 * t + 1] = rsqrtf(d);
    sdeg[c0 + 2 * t + 1] = sqrtf(d);
  }
  if (t == 0 && c0 + nn == N) colptr[N] = E;
  __syncthreads();
  for (int i = estart + t; i < eend; i += 256) {
    int pk = stag[i];
    int pos = atomicAdd(&ldeg[pk & 511], 1);
    csr[pos] = pk >> 9;
  }
}

// ---------------- fused projection tail ----------------
__device__ __forceinline__ void proj_tail(
    const ushort* ylds, float* ssl, float* otile,
    const ushort* __restrict__ wk, const float* __restrict__ biask,
    const float* __restrict__ sdeg, int donorm, float* __restrict__ out,
    int nbase, int koff, int N, int ost, int tid) {
  const int wave = tid >> 6;
  const int lane = tid & 63;
  const int l15 = lane & 15, lhi = lane >> 4;
  f32x4 acc0 = (f32x4)0.f, acc1 = (f32x4)0.f;
  const ushort* ap = ylds + l15 * 136 + lhi * 8;
  const ushort* b0p = wk + ((wave * 32 + l15) << 7) + lhi * 8;
  const ushort* b1p = b0p + (16 << 7);
#pragma unroll
  for (int kk = 0; kk < 4; ++kk) {
    bf16x8 a = *(const bf16x8*)(ap + kk * 32);
    bf16x8 b0 = *(const bf16x8*)(b0p + kk * 32);
    bf16x8 b1 = *(const bf16x8*)(b1p + kk * 32);
    acc0 = __builtin_amdgcn_mfma_f32_16x16x32_bf16(a, b0, acc0, 0, 0, 0);
    acc1 = __builtin_amdgcn_mfma_f32_16x16x32_bf16(a, b1, acc1, 0, 0, 0);
  }
  float s[4];
#pragma unroll
  for (int r = 0; r < 4; ++r) {
    int rg = nbase + lhi * 4 + r;
    s[r] = sdeg[rg < N ? rg : N - 1];
  }
  float bv0 = biask[wave * 32 + l15];
  float bv1 = biask[wave * 32 + 16 + l15];
  float ps[4];
#pragma unroll
  for (int r = 0; r < 4; ++r) {
    acc0[r] = acc0[r] * s[r] + bv0;
    acc1[r] = acc1[r] * s[r] + bv1;
    ps[r] = acc0[r] * acc0[r] + acc1[r] * acc1[r];
  }
#pragma unroll
  for (int m = 1; m < 16; m <<= 1) {
#pragma unroll
    for (int r = 0; r < 4; ++r) ps[r] += __shfl_xor(ps[r], m, 64);
  }
  if (l15 == 0) {
#pragma unroll
    for (int r = 0; r < 4; ++r) ssl[wave * 16 + lhi * 4 + r] = ps[r];
  }
  __syncthreads();
  float sc[4];
#pragma unroll
  for (int r = 0; r < 4; ++r) {
    int rl = lhi * 4 + r;
    float tot = ssl[rl] + ssl[16 + rl] + ssl[32 + rl] + ssl[48 + rl];
    sc[r] = (donorm == 1) ? 1.0f / fmaxf(sqrtf(tot), 1e-12f) : 1.0f;
  }
#pragma unroll
  for (int r = 0; r < 4; ++r) {
    int rl = lhi * 4 + r;
    otile[rl * 132 + wave * 32 + l15] = acc0[r] * sc[r];
    otile[rl * 132 + wave * 32 + 16 + l15] = acc1[r] * sc[r];
  }
  __syncthreads();
#pragma unroll
  for (int i = 0; i < 2; ++i) {
    int idx = tid + 256 * i;
    int rr = idx >> 5, q = idx & 31;
    if (nbase + rr < N) {
      f32x4 vv = *(const f32x4*)&otile[rr * 132 + q * 4];
      __builtin_nontemporal_store(
          vv, (f32x4*)(out + (size_t)(nbase + rr) * ost + koff + q * 4));
    }
  }
}

// ---------------- weightless bf16 hop + fused projection (16-lane groups) ----------------
__device__ __forceinline__ void add8(uint4 v, float& a0, float& a1, float& a2, float& a3,
                                     float& a4, float& a5, float& a6, float& a7) {
  float t0, t1;
  ub2(v.x, t0, t1); a0 += t0; a1 += t1;
  ub2(v.y, t0, t1); a2 += t0; a3 += t1;
  ub2(v.z, t0, t1); a4 += t0; a5 += t1;
  ub2(v.w, t0, t1); a6 += t0; a7 += t1;
}

__global__ __launch_bounds__(256) void k_hopproj(
    const ushort* __restrict__ xin, ushort* __restrict__ yout,
    const ushort* __restrict__ wk, const float* __restrict__ biask,
    const float* __restrict__ sdeg, const float* __restrict__ dinv,
    const int* __restrict__ colptr, const int* __restrict__ csr,
    const int* __restrict__ normp, float* __restrict__ out,
    int koff, int N, int ost, int writeY) {
  __shared__ ushort ylds[16 * 136];
  __shared__ float ssl[64];
  __shared__ float otile[16 * 132];
  const int tid = threadIdx.x;
  const int nbase = blockIdx.x * 16;
  const int node = nbase + (tid >> 4);
  const int g = tid & 15;
  const int nc = node < N ? node : N - 1;

  float di = dinv[nc];
  float w2 = di * di;
  uint4 v = ((const uint4*)(xin + (size_t)nc * 128))[g];
  float a0, a1, a2, a3, a4, a5, a6, a7;
  ub2(v.x, a0, a1); ub2(v.y, a2, a3); ub2(v.z, a4, a5); ub2(v.w, a6, a7);

  int p = colptr[nc], p1 = colptr[nc + 1];
  for (; p + 4 <= p1; p += 4) {
    int s0 = __builtin_nontemporal_load(csr + p);
    int s1 = __builtin_nontemporal_load(csr + p + 1);
    int s2 = __builtin_nontemporal_load(csr + p + 2);
    int s3 = __builtin_nontemporal_load(csr + p + 3);
    uint4 x0 = ((const uint4*)(xin + (size_t)s0 * 128))[g];
    uint4 x1 = ((const uint4*)(xin + (size_t)s1 * 128))[g];
    uint4 x2 = ((const uint4*)(xin + (size_t)s2 * 128))[g];
    uint4 x3 = ((const uint4*)(xin + (size_t)s3 * 128))[g];
    add8(x0, a0, a1, a2, a3, a4, a5, a6, a7);
    add8(x1, a0, a1, a2, a3, a4, a5, a6, a7);
    add8(x2, a0, a1, a2, a3, a4, a5, a6, a7);
    add8(x3, a0, a1, a2, a3, a4, a5, a6, a7);
  }
  for (; p < p1; ++p) {
    int s0 = __builtin_nontemporal_load(csr + p);
    uint4 x0 = ((const uint4*)(xin + (size_t)s0 * 128))[g];
    add8(x0, a0, a1, a2, a3, a4, a5, a6, a7);
  }
  uint4 o;
  o.x = pk2(w2 * a0, w2 * a1);
  o.y = pk2(w2 * a2, w2 * a3);
  o.z = pk2(w2 * a4, w2 * a5);
  o.w = pk2(w2 * a6, w2 * a7);
  if (writeY && node < N) ((uint4*)(yout + (size_t)node * 128))[g] = o;
  *(uint4*)(ylds + (tid >> 4) * 136 + g * 8) = o;
  __syncthreads();

  proj_tail(ylds, ssl, otile, wk, biask, sdeg, normp[0], out, nbase, koff, N,
            ost, tid);
}

// ---------------- y0 = dinv*h (bf16) + fused projection of hop 0 ----------------
__global__ __launch_bounds__(256) void k_y0proj(
    const float* __restrict__ h, ushort* __restrict__ yout,
    const ushort* __restrict__ wk, const float* __restrict__ biask,
    const float* __restrict__ sdeg, const float* __restrict__ dinv,
    const int* __restrict__ normp, float* __restrict__ out, int N, int ost) {
  __shared__ ushort ylds[16 * 136];
  __shared__ float ssl[64];
  __shared__ float otile[16 * 132];
  const int tid = threadIdx.x;
  const int nbase = blockIdx.x * 16;
  const int node = nbase + (tid >> 4);
  const int g = tid & 15;
  const int nc = node < N ? node : N - 1;

  float d = dinv[nc];
  const float4* p = (const float4*)(h + (size_t)nc * 128 + g * 8);
  float4 A = p[0], B = p[1];
  uint4 o;
  o.x = pk2(A.x * d, A.y * d);
  o.y = pk2(A.z * d, A.w * d);
  o.z = pk2(B.x * d, B.y * d);
  o.w = pk2(B.z * d, B.w * d);
  ((uint4*)(yout + (size_t)nc * 128))[g] = o;
  *(uint4*)(ylds + (tid >> 4) * 136 + g * 8) = o;
  __syncthreads();

  proj_tail(ylds, ssl, otile, wk, biask, sdeg, normp[0], out, nbase, 0, N, ost,
            tid);
}

// =================== fp32 fallback path (kept intact) ===================
__global__ void k_zero(uint4* __restrict__ p, int n4) {
  int stride = gridDim.x * blockDim.x;
  for (int i = blockIdx.x * blockDim.x + threadIdx.x; i < n4; i += stride)
    p[i] = make_uint4(0, 0, 0, 0);
}

__global__ void k_deg(const int* __restrict__ col, int* __restrict__ deg, int E) {
  int i = blockIdx.x * blockDim.x + threadIdx.x;
  if (i < E) atomicAdd(&deg[col[i]], 1);
}

__global__ void k_dinv_deg(const int* __restrict__ deg, float* __restrict__ dinv,
                           float* __restrict__ sdeg, int N) {
  int i = blockIdx.x * blockDim.x + threadIdx.x;
  if (i < N) {
    float d = (float)(deg[i] + 1);
    dinv[i] = rsqrtf(d);
    sdeg[i] = sqrtf(d);
  }
}

__global__ void k_scan1(const int* __restrict__ deg, int* __restrict__ colptr,
                        int* __restrict__ part, int N) {
  __shared__ int sd[256];
  int t = threadIdx.x;
  int base = blockIdx.x * 1024 + t * 4;
  int v0 = base + 0 < N ? deg[base + 0] : 0;
  int v1 = base + 1 < N ? deg[base + 1] : 0;
  int v2 = base + 2 < N ? deg[base + 2] : 0;
  int v3 = base + 3 < N ? deg[base + 3] : 0;
  sd[t] = v0 + v1 + v2 + v3;
  __syncthreads();
  for (int off = 1; off < 256; off <<= 1) {
    int val = sd[t];
    int add = (t >= off) ? sd[t - off] : 0;
    __syncthreads();
    sd[t] = val + add;
    __syncthreads();
  }
  int excl = (t > 0) ? sd[t - 1] : 0;
  if (t == 255) part[blockIdx.x] = sd[255];
  if (base + 0 < N) colptr[base + 0] = excl;
  if (base + 1 < N) colptr[base + 1] = excl + v0;
  if (base + 2 < N) colptr[base + 2] = excl + v0 + v1;
  if (base + 3 < N) colptr[base + 3] = excl + v0 + v1 + v2;
}

__global__ void k_scan2(int* __restrict__ part, int nb) {
  __shared__ int sd[1024];
  int t = threadIdx.x;
  sd[t] = (t < nb) ? part[t] : 0;
  __syncthreads();
  for (int off = 1; off < 1024; off <<= 1) {
    int val = sd[t];
    int add = (t >= off) ? sd[t - off] : 0;
    __syncthreads();
    sd[t] = val + add;
    __syncthreads();
  }
  if (t < nb) part[t] = (t > 0) ? sd[t - 1] : 0;
}

__global__ void k_scan3(int* __restrict__ colptr, const int* __restrict__ part, int N, int E) {
  int i = blockIdx.x * blockDim.x + threadIdx.x;
  if (i < N) colptr[i] += part[i >> 10];
  if (i == 0) colptr[N] = E;
}

__global__ void k_fill(const int* __restrict__ row, const int* __restrict__ col,
                       const int* __restrict__ colptr, int* __restrict__ cursor,
                       const float* __restrict__ dinv, int2* __restrict__ csr, int E) {
  int stride = gridDim.x * blockDim.x;
  for (int i = blockIdx.x * blockDim.x + threadIdx.x; i < E; i += stride) {
    int r = row[i], c = col[i];
    int pos = colptr[c] + atomicAdd(&cursor[c], 1);
    int2 v;
    v.x = r;
    v.y = __float_as_int(dinv[r] * dinv[c]);
    csr[pos] = v;
  }
}

__global__ void k_wt(const float* __restrict__ W, float* __restrict__ Wt, int total) {
  int i = blockIdx.x * blockDim.x + threadIdx.x;
  if (i < total) {
    int k = i >> 14, rem = i & 16383, h = rem >> 7, f = rem & 127;
    Wt[(k << 14) + f * 128 + h] = W[i];
  }
}

__global__ __launch_bounds__(256) void k_hop(
    const float* __restrict__ xsrc, int xstride,
    float* __restrict__ out, int dst_off, int ost,
    const int* __restrict__ colptr, const int2* __restrict__ csr,
    const float* __restrict__ dinv, int N) {
  int gid = blockIdx.x * blockDim.x + threadIdx.x;
  int node = gid >> 5, lane = gid & 31;
  if (node >= N) return;
  float di = dinv[node];
  float4 acc = *(const float4*)(xsrc + (size_t)node * xstride + lane * 4);
  float w = di * di;
  acc.x *= w; acc.y *= w; acc.z *= w; acc.w *= w;
  int p1 = colptr[node + 1];
  for (int p = colptr[node]; p < p1; ++p) {
    int2 ev = csr[p];
    float v = __int_as_float(ev.y);
    float4 x = *(const float4*)(xsrc + (size_t)ev.x * xstride + lane * 4);
    acc.x += v * x.x; acc.y += v * x.y; acc.z += v * x.z; acc.w += v * x.w;
  }
  *(float4*)(out + (size_t)node * ost + dst_off + lane * 4) = acc;
}

__global__ __launch_bounds__(256) void k_gemm(
    const float* __restrict__ h, const float* __restrict__ Wt_g,
    const float* __restrict__ bias, const int* __restrict__ normp,
    float* __restrict__ out, int N, int ost) {
  __shared__ float Wt[128 * 128];
  __shared__ float xl[32 * 128];
  const int k = blockIdx.y;
  const int row0 = blockIdx.x * 32;
  const int tid = threadIdx.x;
  const float4* Wg4 = (const float4*)(Wt_g + ((size_t)k << 14));
  float4* Wt4 = (float4*)Wt;
#pragma unroll
  for (int i = 0; i < 16; ++i) Wt4[tid + 256 * i] = Wg4[tid + 256 * i];
  const float* xs = (k == 0) ? h : (out + k * 128);
  const int xst = (k == 0) ? 128 : ost;
  float4* xl4 = (float4*)xl;
#pragma unroll
  for (int i = 0; i < 4; ++i) {
    int idx = tid + 256 * i;
    int r = idx >> 5, fq = idx & 31;
    int rg = row0 + r;
    if (rg >= N) rg = N - 1;
    xl4[idx] = *((const float4*)(xs + (size_t)rg * xst) + fq);
  }
  __syncthreads();
  const int hq = tid & 31;
  const int rq = tid >> 5;
  float acc[4][4] = {{0.f}};
  const float* xb = xl + rq * 4 * 128;
#pragma unroll 4
  for (int f = 0; f < 128; ++f) {
    float4 wv = *(const float4*)(Wt + f * 128 + hq * 4);
    float x0 = xb[f];
    float x1 = xb[128 + f];
    float x2 = xb[256 + f];
    float x3 = xb[384 + f];
    acc[0][0] += x0 * wv.x; acc[0][1] += x0 * wv.y; acc[0][2] += x0 * wv.z; acc[0][3] += x0 * wv.w;
    acc[1][0] += x1 * wv.x; acc[1][1] += x1 * wv.y; acc[1][2] += x1 * wv.z; acc[1][3] += x1 * wv.w;
    acc[2][0] += x2 * wv.x; acc[2][1] += x2 * wv.y; acc[2][2] += x2 * wv.z; acc[2][3] += x2 * wv.w;
    acc[3][0] += x3 * wv.x; acc[3][1] += x3 * wv.y; acc[3][2] += x3 * wv.z; acc[3][3] += x3 * wv.w;
  }
  float4 bv = *((const float4*)(bias + (size_t)k * 128) + hq);
#pragma unroll
  for (int rl = 0; rl < 4; ++rl) {
    acc[rl][0] += bv.x; acc[rl][1] += bv.y; acc[rl][2] += bv.z; acc[rl][3] += bv.w;
  }
  float ss[4];
#pragma unroll
  for (int rl = 0; rl < 4; ++rl)
    ss[rl] = acc[rl][0] * acc[rl][0] + acc[rl][1] * acc[rl][1] +
             acc[rl][2] * acc[rl][2] + acc[rl][3] * acc[rl][3];
#pragma unroll
  for (int m = 1; m < 32; m <<= 1) {
#pragma unroll
    for (int rl = 0; rl < 4; ++rl) ss[rl] += __shfl_xor(ss[rl], m, 64);
  }
  const int donorm = normp[0];
#pragma unroll
  for (int rl = 0; rl < 4; ++rl) {
    float sc = 1.0f;
    if (donorm == 1) sc = 1.0f / fmaxf(sqrtf(ss[rl]), 1e-12f);
    int rg = row0 + rq * 4 + rl;
    if (rg < N) {
      float4 oo;
      oo.x = acc[rl][0] * sc; oo.y = acc[rl][1] * sc;
      oo.z = acc[rl][2] * sc; oo.w = acc[rl][3] * sc;
      *((float4*)(out + (size_t)rg * ost + k * 128) + hq) = oo;
    }
  }
}

extern "C" void kernel_launch(void* const* d_in, const int* in_sizes, int n_in,
                              void* d_out, int out_size, void* d_ws, size_t ws_size,
                              hipStream_t stream) {
  const float* h = (const float*)d_in[0];
  const int* ei = (const int*)d_in[1];
  const int* normp = (const int*)d_in[2];
  const float* W = (const float*)d_in[3];
  const float* bias = (const float*)d_in[4];
  float* out = (float*)d_out;

  const int N = in_sizes[0] / 128;
  const int E = in_sizes[1] / 2;
  const int KP1 = in_sizes[3] / (128 * 128);
  const int OST = KP1 * 128;
  const int* row = ei;
  const int* col = ei + E;

  char* ws = (char*)d_ws;
  size_t used = 0;
  auto carve = [&](size_t bytes) {
    char* p = ws + used;
    used += (bytes + 255) & ~(size_t)255;
    return p;
  };
  int* colptr = (int*)carve((size_t)(N + 1) * 4);
  float* dinv = (float*)carve((size_t)N * 4);
  float* sdeg = (float*)carve((size_t)N * 4);

  const size_t al = 255;
  const size_t bucketable = (size_t)N <= 131072 ? 1 : 0;
  const size_t gB = 256 * 256 * 4;
  const size_t needBf = used + 2 * ((gB + al) & ~al) + 4096 +
                        2 * (((size_t)E * 4 + al) & ~al) +
                        (((size_t)KP1 * 128 * 128 * 2 + al) & ~al) +
                        2 * (((size_t)N * 128 * 2 + al) & ~al);

  if (bucketable && ws_size >= needBf) {
    // ---------------- bf16 fused path, bucketed CSR ----------------
    int* G = (int*)carve(gB);
    int* OFF = (int*)carve(gB);
    int* bstart = (int*)carve(4096);
    int* stag = (int*)carve((size_t)E * 4);
    int* csr = (int*)carve((size_t)E * 4);
    ushort* Wb = (ushort*)carve((size_t)KP1 * 128 * 128 * 2);
    ushort* bufA = (ushort*)carve((size_t)N * 128 * 2);
    ushort* bufB = (ushort*)carve((size_t)N * 128 * 2);

    const int C = (E + 255) / 256;
    const int NBUK = (N + 511) >> 9;

    k_bcount<<<256, 256, 0, stream>>>(col, G, E, C, W, Wb, KP1 * 2048);
    k_bscan<<<1, 256, 0, stream>>>(G, OFF, bstart, E);
    k_bstage<<<256, 256, 0, stream>>>(row, col, OFF, stag, E, C);
    k_bcsr<<<NBUK, 256, 0, stream>>>(stag, bstart, colptr, csr, dinv, sdeg, N, E);

    int gb = (N + 15) / 16;
    k_y0proj<<<gb, 256, 0, stream>>>(h, bufA, Wb, bias, sdeg, dinv, normp, out,
                                     N, OST);
    ushort* cur = bufA;
    ushort* nxt = bufB;
    for (int kk = 1; kk < KP1; ++kk) {
      k_hopproj<<<gb, 256, 0, stream>>>(
          cur, nxt, Wb + (kk << 14), bias + kk * 128, sdeg, dinv, colptr, csr,
          normp, out, kk * 128, N, OST, (kk < KP1 - 1) ? 1 : 0);
      ushort* t = cur; cur = nxt; nxt = t;
    }
  } else {
    // ---------------- fp32 fallback (old preprocessing) ----------------
    int* deg = (int*)carve((size_t)N * 4);
    int* part = (int*)carve(4096);
    int* cursor = (int*)carve((size_t)N * 4);
    int2* csr2 = (int2*)carve((size_t)E * 8);
    float* Wt_g = (float*)carve((size_t)KP1 * 128 * 128 * 4);
    const int eb = (E + 255) / 256;
    const int nblk = (N + 255) / 256;
    k_zero<<<32, 256, 0, stream>>>((uint4*)deg, (N + 3) / 4);
    k_zero<<<32, 256, 0, stream>>>((uint4*)cursor, (N + 3) / 4);
    k_deg<<<eb, 256, 0, stream>>>(col, deg, E);
    k_dinv_deg<<<nblk, 256, 0, stream>>>(deg, dinv, sdeg, N);
    int nb = (N + 1023) / 1024;
    k_scan1<<<nb, 256, 0, stream>>>(deg, colptr, part, N);
    k_scan2<<<1, 1024, 0, stream>>>(part, nb);
    k_scan3<<<nblk, 256, 0, stream>>>(colptr, part, N, E);
    k_fill<<<1024, 256, 0, stream>>>(row, col, colptr, cursor, dinv, csr2, E);
    k_wt<<<(KP1 * 16384 + 255) / 256, 256, 0, stream>>>(W, Wt_g, KP1 * 16384);
    int hopBlocks = (N * 32 + 255) / 256;
    for (int kk = 1; kk < KP1; ++kk) {
      const float* src = (kk == 1) ? h : (out + (kk - 1) * 128);
      int st = (kk == 1) ? 128 : OST;
      k_hop<<<hopBlocks, 256, 0, stream>>>(src, st, out, kk * 128, OST,
                                           colptr, csr2, dinv, N);
    }
    k_gemm<<<dim3((N + 31) / 32, KP1), 256, 0, stream>>>(h, Wt_g, bias, normp,
                                                         out, N, OST);
  }
}